// Round 1
// baseline (272.746 us; speedup 1.0000x reference)
//
#include <hip/hip_runtime.h>
#include <cstdint>
#include <cstddef>

// Problem constants
#define BB  4
#define QQ  2048
#define SK  2048   // key length
#define DD  512
#define HH  8
#define DHH 64

typedef __bf16 bf16;
typedef bf16  bf16x8 __attribute__((ext_vector_type(8)));
typedef bf16  bf16x4 __attribute__((ext_vector_type(4)));
typedef float f32x4  __attribute__((ext_vector_type(4)));

// ---- async global->LDS 16B copy (wave-uniform base + lane*16 semantics) ----
__device__ __forceinline__ void async16(void* lds, const void* g) {
  __builtin_amdgcn_global_load_lds(
      (const __attribute__((address_space(1))) unsigned int*)g,
      (__attribute__((address_space(3))) unsigned int*)lds, 16, 0, 0);
}

// ---- f32 -> bf16 elementwise convert (float4 per thread) ----
__global__ __launch_bounds__(256) void cvt_f32_bf16(
    const float* __restrict__ src, bf16* __restrict__ dst, int n4) {
  int i = blockIdx.x * 256 + threadIdx.x;
  if (i < n4) {
    float4 v = ((const float4*)src)[i];
    bf16x4 o;
    o[0] = (bf16)v.x; o[1] = (bf16)v.y; o[2] = (bf16)v.z; o[3] = (bf16)v.w;
    ((bf16x4*)dst)[i] = o;
  }
}

// ---- GEMM: C[M,512] = A[M,512] @ Bt[512,512]^T  (Bt rows contiguous in k) ----
// 128x128 tile, BK=64, 4 waves (2x2), each wave 64x64 via 4x4 MFMA 16x16x32.
// EPI 0: bf16 out to heads layout [B,H,S,DH]
// EPI 1: f32 out plain [M,512]
// EPI 2: bf16 out transposed-per-head [B,H,DH,S]   (for V)
template <int EPI>
__global__ __launch_bounds__(256, 2) void gemm_bt(
    const bf16* __restrict__ A, const bf16* __restrict__ Bt,
    void* __restrict__ Cout, int Kd) {
  __shared__ __align__(16) bf16 lA[128 * 64];
  __shared__ __align__(16) bf16 lB[128 * 64];
  const int tid  = threadIdx.x;
  const int l    = tid & 63;
  const int w    = tid >> 6;
  const int lrow = l & 15, lq = l >> 4;
  const int wm = (w >> 1) * 64, wn = (w & 1) * 64;
  const int tM = blockIdx.y * 128, tN = blockIdx.x * 128;

  f32x4 acc[4][4] = {};

  for (int kt = 0; kt < Kd; kt += 64) {
    __syncthreads();
#pragma unroll
    for (int j = 0; j < 4; ++j) {
      int c = j * 256 + tid;              // 16B chunk id, 0..1023
      int row = c >> 3, col = (c & 7) << 3;
      async16(&lA[c * 8], &A[(size_t)(tM + row) * Kd + kt + col]);
    }
#pragma unroll
    for (int j = 0; j < 4; ++j) {
      int c = j * 256 + tid;
      int row = c >> 3, col = (c & 7) << 3;
      async16(&lB[c * 8], &Bt[(size_t)(tN + row) * Kd + kt + col]);
    }
    __syncthreads();                      // drains vmcnt -> LDS valid

#pragma unroll
    for (int ks = 0; ks < 2; ++ks) {
      bf16x8 af[4], bfr[4];
#pragma unroll
      for (int mt = 0; mt < 4; ++mt)
        af[mt] = *(const bf16x8*)&lA[(wm + mt * 16 + lrow) * 64 + ks * 32 + lq * 8];
#pragma unroll
      for (int nt = 0; nt < 4; ++nt)
        bfr[nt] = *(const bf16x8*)&lB[(wn + nt * 16 + lrow) * 64 + ks * 32 + lq * 8];
#pragma unroll
      for (int mt = 0; mt < 4; ++mt)
#pragma unroll
        for (int nt = 0; nt < 4; ++nt)
          acc[mt][nt] = __builtin_amdgcn_mfma_f32_16x16x32_bf16(
              af[mt], bfr[nt], acc[mt][nt], 0, 0, 0);
    }
  }

  // epilogue: C/D layout col=lane&15, row=(lane>>4)*4+reg
#pragma unroll
  for (int mt = 0; mt < 4; ++mt) {
#pragma unroll
    for (int nt = 0; nt < 4; ++nt) {
      int gi0 = tM + wm + mt * 16 + lq * 4;   // output row base (token idx)
      int gc  = tN + wn + nt * 16 + lrow;     // output col (h*64+dh)
      if (EPI == 2) {
        // vt[b][h][dh][s], 4 consecutive s per lane -> 8B packed store
        int b = gi0 >> 11, s0 = gi0 & 2047;
        int h = gc >> 6,  dh = gc & 63;
        bf16x4 o;
#pragma unroll
        for (int r = 0; r < 4; ++r) o[r] = (bf16)acc[mt][nt][r];
        *(bf16x4*)&((bf16*)Cout)[((size_t)(b * HH + h) * DHH + dh) * SK + s0] = o;
      } else {
#pragma unroll
        for (int r = 0; r < 4; ++r) {
          int gi = gi0 + r;
          if (EPI == 0) {
            int b = gi >> 11, s = gi & 2047;
            int h = gc >> 6,  dh = gc & 63;
            ((bf16*)Cout)[((size_t)(b * HH + h) * QQ + s) * DHH + dh] =
                (bf16)acc[mt][nt][r];
          } else {
            ((float*)Cout)[(size_t)gi * DD + gc] = acc[mt][nt][r];
          }
        }
      }
    }
  }
}

// ---- Flash attention: per (b,h, 128-row q-tile); K-tiles of 64 ----
__global__ __launch_bounds__(256, 2) void attn(
    const bf16* __restrict__ qh, const bf16* __restrict__ kh,
    const bf16* __restrict__ vt, const int* __restrict__ valid_lens,
    bf16* __restrict__ ao) {
  __shared__ __align__(16) bf16 lQ[128 * 64];   // reused as P (wave-private rows)
  __shared__ __align__(16) bf16 lK[64 * 64];
  __shared__ __align__(16) bf16 lV[64 * 64];    // vt tile: [dh][key]
  const int tid  = threadIdx.x;
  const int l    = tid & 63;
  const int w    = tid >> 6;
  const int lrow = l & 15, lq = l >> 4;
  const int bh = blockIdx.y;
  const int b = bh >> 3, h = bh & 7;
  const int qtile = blockIdx.x * 128;
  const bf16* qbase = qh + (size_t)bh * QQ * DHH;
  const bf16* kbase = kh + (size_t)bh * SK * DHH;
  const bf16* vbase = vt + (size_t)bh * DHH * SK;
  const int vl  = valid_lens[b];
  const int nkt = (vl + 63) >> 6;

  // stage this wave's 32 Q rows (wave-private region of lQ)
#pragma unroll
  for (int j = 0; j < 4; ++j) {
    int c = j * 64 + l;                   // 0..255 within wave region
    int row = w * 32 + (c >> 3);
    int col = (c & 7) << 3;
    async16(&lQ[w * 2048 + c * 8], &qbase[(size_t)(qtile + row) * DHH + col]);
  }
  __syncthreads();                         // vmcnt drain

  bf16x8 aq[2][2];
#pragma unroll
  for (int mt = 0; mt < 2; ++mt)
#pragma unroll
    for (int ks = 0; ks < 2; ++ks)
      aq[mt][ks] = *(const bf16x8*)&lQ[(w * 32 + mt * 16 + lrow) * 64 + ks * 32 + lq * 8];

  f32x4 acc[2][4] = {};
  float mold[2][4], lsum[2][4];
#pragma unroll
  for (int mt = 0; mt < 2; ++mt)
#pragma unroll
    for (int r = 0; r < 4; ++r) { mold[mt][r] = -1e30f; lsum[mt][r] = 0.f; }

  const float cscale = 0.125f * 1.44269504088896340736f;  // 1/sqrt(64) * log2(e)

  for (int kt = 0; kt < nkt; ++kt) {
    const int k0 = kt * 64;
    __syncthreads();                       // protect lK/lV from prev iter readers
#pragma unroll
    for (int j = 0; j < 2; ++j) {
      int c = j * 256 + tid;
      int row = c >> 3, col = (c & 7) << 3;
      async16(&lK[c * 8], &kbase[(size_t)(k0 + row) * DHH + col]);
    }
#pragma unroll
    for (int j = 0; j < 2; ++j) {
      int c = j * 256 + tid;
      int row = c >> 3, col = (c & 7) << 3;
      async16(&lV[c * 8], &vbase[(size_t)row * SK + k0 + col]);
    }
    __syncthreads();

    // S = Q @ K^T  (A = q rows, B^T = kh rows)
    f32x4 s[2][4] = {};
#pragma unroll
    for (int ks = 0; ks < 2; ++ks) {
      bf16x8 bk[4];
#pragma unroll
      for (int nt = 0; nt < 4; ++nt)
        bk[nt] = *(const bf16x8*)&lK[(nt * 16 + lrow) * 64 + ks * 32 + lq * 8];
#pragma unroll
      for (int mt = 0; mt < 2; ++mt)
#pragma unroll
        for (int nt = 0; nt < 4; ++nt)
          s[mt][nt] = __builtin_amdgcn_mfma_f32_16x16x32_bf16(
              aq[mt][ks], bk[nt], s[mt][nt], 0, 0, 0);
    }

    // scale + mask (z-domain: exp2)
#pragma unroll
    for (int mt = 0; mt < 2; ++mt)
#pragma unroll
      for (int nt = 0; nt < 4; ++nt) {
        bool valid = (k0 + nt * 16 + lrow) < vl;
#pragma unroll
        for (int r = 0; r < 4; ++r)
          s[mt][nt][r] = valid ? s[mt][nt][r] * cscale : -1e30f;
      }

    // online softmax per row; row = mt*16 + lq*4 + r, cols across 16 lanes
#pragma unroll
    for (int mt = 0; mt < 2; ++mt) {
#pragma unroll
      for (int r = 0; r < 4; ++r) {
        float zm = fmaxf(fmaxf(s[mt][0][r], s[mt][1][r]),
                         fmaxf(s[mt][2][r], s[mt][3][r]));
        zm = fmaxf(zm, __shfl_xor(zm, 1));
        zm = fmaxf(zm, __shfl_xor(zm, 2));
        zm = fmaxf(zm, __shfl_xor(zm, 4));
        zm = fmaxf(zm, __shfl_xor(zm, 8));
        float mnew  = fmaxf(mold[mt][r], zm);
        float alpha = exp2f(mold[mt][r] - mnew);
        float rs = 0.f;
#pragma unroll
        for (int nt = 0; nt < 4; ++nt) {
          float p = exp2f(s[mt][nt][r] - mnew);   // masked -> 0 exactly
          s[mt][nt][r] = p;
          rs += p;
        }
        rs += __shfl_xor(rs, 1);
        rs += __shfl_xor(rs, 2);
        rs += __shfl_xor(rs, 4);
        rs += __shfl_xor(rs, 8);
        lsum[mt][r] = lsum[mt][r] * alpha + rs;
        mold[mt][r] = mnew;
#pragma unroll
        for (int nt = 0; nt < 4; ++nt) acc[mt][nt][r] *= alpha;
        // write P (C-layout) into LDS as [row][key] bf16 (wave-private rows)
#pragma unroll
        for (int nt = 0; nt < 4; ++nt)
          lQ[(w * 32 + mt * 16 + lq * 4 + r) * 64 + nt * 16 + lrow] =
              (bf16)s[mt][nt][r];
      }
    }

    // O += P @ V   (A = P rows from LDS, B^T = vt rows [dh][key])
#pragma unroll
    for (int ks = 0; ks < 2; ++ks) {
      bf16x8 ap[2], bv[4];
#pragma unroll
      for (int mt = 0; mt < 2; ++mt)
        ap[mt] = *(const bf16x8*)&lQ[(w * 32 + mt * 16 + lrow) * 64 + ks * 32 + lq * 8];
#pragma unroll
      for (int nt = 0; nt < 4; ++nt)
        bv[nt] = *(const bf16x8*)&lV[(nt * 16 + lrow) * 64 + ks * 32 + lq * 8];
#pragma unroll
      for (int mt = 0; mt < 2; ++mt)
#pragma unroll
        for (int nt = 0; nt < 4; ++nt)
          acc[mt][nt] = __builtin_amdgcn_mfma_f32_16x16x32_bf16(
              ap[mt], bv[nt], acc[mt][nt], 0, 0, 0);
    }
  }

  // epilogue: ao[b][s][h*64+dh] bf16
#pragma unroll
  for (int mt = 0; mt < 2; ++mt) {
#pragma unroll
    for (int r = 0; r < 4; ++r) {
      float inv = 1.0f / lsum[mt][r];
      int srow = qtile + w * 32 + mt * 16 + lq * 4 + r;
#pragma unroll
      for (int nt = 0; nt < 4; ++nt) {
        int col = h * 64 + nt * 16 + lrow;
        ao[((size_t)(b * QQ + srow)) * DD + col] = (bf16)(acc[mt][nt][r] * inv);
      }
    }
  }
}

extern "C" void kernel_launch(void* const* d_in, const int* in_sizes, int n_in,
                              void* d_out, int out_size, void* d_ws, size_t ws_size,
                              hipStream_t stream) {
  const float* queries    = (const float*)d_in[0];
  const float* keys       = (const float*)d_in[1];
  const float* values     = (const float*)d_in[2];
  const int*   valid_lens = (const int*)d_in[3];
  const float* W_q = (const float*)d_in[4];
  const float* W_k = (const float*)d_in[5];
  const float* W_v = (const float*)d_in[6];
  const float* W_o = (const float*)d_in[7];

  const size_t NX = (size_t)BB * QQ * DD;   // 4194304
  const size_t NW = (size_t)DD * DD;        // 262144

  bf16* xq = (bf16*)d_ws;       // bf16 inputs
  bf16* xk = xq + NX;
  bf16* xv = xk + NX;
  bf16* wq = xv + NX;           // bf16 weights
  bf16* wk = wq + NW;
  bf16* wv = wk + NW;
  bf16* wo = wv + NW;
  bf16* qh = wo + NW;           // [B,H,S,DH]
  bf16* kh = qh + NX;           // [B,H,S,DH]
  bf16* vt = kh + NX;           // [B,H,DH,S]
  bf16* ao = xq;                // reuse xq region (projections finished by then)

  dim3 blk(256);
  cvt_f32_bf16<<<NX / 1024, blk, 0, stream>>>(queries, xq, NX / 4);
  cvt_f32_bf16<<<NX / 1024, blk, 0, stream>>>(keys,    xk, NX / 4);
  cvt_f32_bf16<<<NX / 1024, blk, 0, stream>>>(values,  xv, NX / 4);
  cvt_f32_bf16<<<NW / 1024, blk, 0, stream>>>(W_q, wq, NW / 4);
  cvt_f32_bf16<<<NW / 1024, blk, 0, stream>>>(W_k, wk, NW / 4);
  cvt_f32_bf16<<<NW / 1024, blk, 0, stream>>>(W_v, wv, NW / 4);
  cvt_f32_bf16<<<NW / 1024, blk, 0, stream>>>(W_o, wo, NW / 4);

  dim3 gg(DD / 128, (BB * QQ) / 128);   // (4, 64)
  gemm_bt<0><<<gg, blk, 0, stream>>>(xq, wq, qh, DD);
  gemm_bt<0><<<gg, blk, 0, stream>>>(xk, wk, kh, DD);
  gemm_bt<2><<<gg, blk, 0, stream>>>(xv, wv, vt, DD);

  attn<<<dim3(QQ / 128, BB * HH), blk, 0, stream>>>(qh, kh, vt, valid_lens, ao);

  gemm_bt<1><<<gg, blk, 0, stream>>>(ao, wo, d_out, DD);
}

// Round 2
// 210.722 us; speedup vs baseline: 1.2943x; 1.2943x over previous
//
#include <hip/hip_runtime.h>
#include <cstdint>
#include <cstddef>

// Problem constants
#define BB  4
#define QQ  2048
#define SK  2048   // key length
#define DD  512
#define HH  8
#define DHH 64

typedef __bf16 bf16;
typedef bf16  bf16x8 __attribute__((ext_vector_type(8)));
typedef bf16  bf16x4 __attribute__((ext_vector_type(4)));
typedef float f32x4  __attribute__((ext_vector_type(4)));

// ---- async global->LDS 16B copy (wave-uniform base + lane*16 semantics) ----
__device__ __forceinline__ void async16(void* lds, const void* g) {
  __builtin_amdgcn_global_load_lds(
      (const __attribute__((address_space(1))) unsigned int*)g,
      (__attribute__((address_space(3))) unsigned int*)lds, 16, 0, 0);
}

// ---- batched f32 -> bf16 converts (blockIdx.y selects tensor) ----
__global__ __launch_bounds__(256) void cvt3(
    const float* __restrict__ s0, const float* __restrict__ s1,
    const float* __restrict__ s2, bf16* __restrict__ d0,
    bf16* __restrict__ d1, bf16* __restrict__ d2, int n4) {
  const float* s = blockIdx.y == 0 ? s0 : blockIdx.y == 1 ? s1 : s2;
  bf16*        d = blockIdx.y == 0 ? d0 : blockIdx.y == 1 ? d1 : d2;
  int i = blockIdx.x * 256 + threadIdx.x;
  if (i < n4) {
    float4 v = ((const float4*)s)[i];
    bf16x4 o;
    o[0] = (bf16)v.x; o[1] = (bf16)v.y; o[2] = (bf16)v.z; o[3] = (bf16)v.w;
    ((bf16x4*)d)[i] = o;
  }
}

__global__ __launch_bounds__(256) void cvt4(
    const float* __restrict__ s0, const float* __restrict__ s1,
    const float* __restrict__ s2, const float* __restrict__ s3,
    bf16* __restrict__ d0, bf16* __restrict__ d1,
    bf16* __restrict__ d2, bf16* __restrict__ d3, int n4) {
  const float* s = blockIdx.y == 0 ? s0 : blockIdx.y == 1 ? s1
                 : blockIdx.y == 2 ? s2 : s3;
  bf16*        d = blockIdx.y == 0 ? d0 : blockIdx.y == 1 ? d1
                 : blockIdx.y == 2 ? d2 : d3;
  int i = blockIdx.x * 256 + threadIdx.x;
  if (i < n4) {
    float4 v = ((const float4*)s)[i];
    bf16x4 o;
    o[0] = (bf16)v.x; o[1] = (bf16)v.y; o[2] = (bf16)v.z; o[3] = (bf16)v.w;
    ((bf16x4*)d)[i] = o;
  }
}

// ---- GEMM: C[M,512] = A[M,512] @ Bt[512,512]^T ----
// 128x64 tile, BK=64, double-buffered (1 barrier/iter), XOR-swizzled LDS.
// 4 waves (2x2): wave does 64x32 via 4x2 MFMA 16x16x32.
// EPI 0: bf16 out, heads layout [B,H,S,DH], scaled by `scale`
// EPI 1: f32 out plain [M,512]
// EPI 2: bf16 out transposed-per-head [B,H,DH,S]   (for V)
template <int EPI>
__global__ __launch_bounds__(256, 2) void gemm_bt(
    const bf16* __restrict__ A, const bf16* __restrict__ Bt,
    void* __restrict__ Cout, float scale) {
  __shared__ __align__(16) bf16 lA[2][128 * 64];
  __shared__ __align__(16) bf16 lB[2][64 * 64];
  const int tid  = threadIdx.x;
  const int l    = tid & 63;
  const int w    = tid >> 6;
  const int lrow = l & 15, lq = l >> 4;
  const int wm = (w >> 1) * 64, wn = (w & 1) * 32;
  const int tM = blockIdx.y * 128, tN = blockIdx.x * 64;

  auto stage = [&](int kt, int buf) {
#pragma unroll
    for (int j = 0; j < 4; ++j) {
      int c = j * 256 + tid, row = c >> 3, gcc = (c & 7) ^ (row & 7);
      async16(&lA[buf][c * 8], &A[(size_t)(tM + row) * DD + kt + gcc * 8]);
    }
#pragma unroll
    for (int j = 0; j < 2; ++j) {
      int c = j * 256 + tid, row = c >> 3, gcc = (c & 7) ^ (row & 7);
      async16(&lB[buf][c * 8], &Bt[(size_t)(tN + row) * DD + kt + gcc * 8]);
    }
  };

  f32x4 acc[4][2] = {};
  stage(0, 0);
  for (int it = 0; it < 8; ++it) {
    __syncthreads();                     // drains stage(it)
    if (it + 1 < 8) stage((it + 1) * 64, (it + 1) & 1);   // in flight over compute
    const bf16* bufA = lA[it & 1];
    const bf16* bufB = lB[it & 1];
#pragma unroll
    for (int ks = 0; ks < 2; ++ks) {
      bf16x8 af[4], bfr[2];
#pragma unroll
      for (int mt = 0; mt < 4; ++mt) {
        int row = wm + mt * 16 + lrow;
        int chunk = row * 8 + ((ks * 4 + lq) ^ (lrow & 7));
        af[mt] = *(const bf16x8*)&bufA[chunk * 8];
      }
#pragma unroll
      for (int nt = 0; nt < 2; ++nt) {
        int row = wn + nt * 16 + lrow;
        int chunk = row * 8 + ((ks * 4 + lq) ^ (lrow & 7));
        bfr[nt] = *(const bf16x8*)&bufB[chunk * 8];
      }
#pragma unroll
      for (int mt = 0; mt < 4; ++mt)
#pragma unroll
        for (int nt = 0; nt < 2; ++nt)
          acc[mt][nt] = __builtin_amdgcn_mfma_f32_16x16x32_bf16(
              af[mt], bfr[nt], acc[mt][nt], 0, 0, 0);
    }
  }

  // epilogue: C/D layout col=lane&15, row=(lane>>4)*4+reg
#pragma unroll
  for (int mt = 0; mt < 4; ++mt) {
#pragma unroll
    for (int nt = 0; nt < 2; ++nt) {
      int gi0 = tM + wm + mt * 16 + lq * 4;   // output row base (token idx)
      int gc  = tN + wn + nt * 16 + lrow;     // output col (h*64+dh)
      if (EPI == 2) {
        int b2 = gi0 >> 11, s0 = gi0 & 2047;
        int h2 = gc >> 6,  dh = gc & 63;
        bf16x4 o;
#pragma unroll
        for (int r = 0; r < 4; ++r) o[r] = (bf16)acc[mt][nt][r];
        *(bf16x4*)&((bf16*)Cout)[((size_t)(b2 * HH + h2) * DHH + dh) * SK + s0] = o;
      } else if (EPI == 0) {
#pragma unroll
        for (int r = 0; r < 4; ++r) {
          int gi = gi0 + r;
          int b2 = gi >> 11, s = gi & 2047;
          int h2 = gc >> 6,  dh = gc & 63;
          ((bf16*)Cout)[((size_t)(b2 * HH + h2) * QQ + s) * DHH + dh] =
              (bf16)(acc[mt][nt][r] * scale);
        }
      } else {
#pragma unroll
        for (int r = 0; r < 4; ++r)
          ((float*)Cout)[(size_t)(gi0 + r) * DD + gc] = acc[mt][nt][r];
      }
    }
  }
}

// ---- Flash attention, transposed (S^T = K·Q^T), in-register softmax ----
// Block = 4 waves; each wave owns 16 queries (C-layout cols). 64-key tiles,
// double-buffered K/V staging, one barrier per iter, XOR-swizzled LDS.
// P stays in registers: S^T C-layout quads concat pairwise into the PV
// B-operand (k = quad*8+j <-> two 16-key C tiles).
__global__ __launch_bounds__(256, 4) void attn(
    const bf16* __restrict__ qh, const bf16* __restrict__ kh,
    const bf16* __restrict__ vt, const int* __restrict__ valid_lens,
    bf16* __restrict__ ao) {
  __shared__ __align__(16) bf16 lK[2][64 * 64];   // [key][dh], swizzled
  __shared__ __align__(16) bf16 lV[2][64 * 64];   // [dh][key], swizzled
  const int tid  = threadIdx.x;
  const int l    = tid & 63;
  const int w    = tid >> 6;
  const int lrow = l & 15, lq = l >> 4;
  const int rx   = lrow & 7;                      // swizzle key for reads
  const int bh = blockIdx.y;
  const int b = bh >> 3, h = bh & 7;
  const int q0 = blockIdx.x * 64 + w * 16;        // this wave's first query
  const bf16* qbase = qh + (size_t)bh * QQ * DHH;
  const bf16* kbase = kh + (size_t)bh * SK * DHH;
  const bf16* vbase = vt + (size_t)bh * DHH * SK;
  const int vl  = valid_lens[b];
  const int nkt = (vl + 63) >> 6;

  // Q fragments direct from global (B-operand: n=lane&15=query, k=quad*8+j)
  bf16x8 qf[2];
#pragma unroll
  for (int ks = 0; ks < 2; ++ks)
    qf[ks] = *(const bf16x8*)&qbase[(size_t)(q0 + lrow) * DHH + ks * 32 + lq * 8];

  auto stageKV = [&](int k0, int buf) {
#pragma unroll
    for (int j = 0; j < 2; ++j) {
      int c = j * 256 + tid, row = c >> 3, gcc = (c & 7) ^ (row & 7);
      async16(&lK[buf][c * 8], &kbase[(size_t)(k0 + row) * DHH + gcc * 8]);
    }
#pragma unroll
    for (int j = 0; j < 2; ++j) {
      int c = j * 256 + tid, row = c >> 3, gcc = (c & 7) ^ (row & 7);
      async16(&lV[buf][c * 8], &vbase[(size_t)row * SK + k0 + gcc * 8]);
    }
  };

  f32x4 acc[4] = {};                     // O^T[dh=mt*16+lq*4+r][q=lrow]
  float mold = -1e30f, lsum = 0.f;       // per-lane = per-query scalars

  stageKV(0, 0);
  for (int kt = 0; kt < nkt; ++kt) {
    __syncthreads();                     // drains stage(kt)
    if (kt + 1 < nkt) stageKV((kt + 1) * 64, (kt + 1) & 1);
    const bf16* bufK = lK[kt & 1];
    const bf16* bufV = lV[kt & 1];
    const int k0 = kt * 64;

    // S^T = K · Q^T : A = K rows (m=key), B = Q (n=query)
    f32x4 s[4] = {};
#pragma unroll
    for (int ks = 0; ks < 2; ++ks) {
#pragma unroll
      for (int t = 0; t < 4; ++t) {
        int row = t * 16 + lrow;
        int chunk = row * 8 + ((ks * 4 + lq) ^ rx);
        bf16x8 kf = *(const bf16x8*)&bufK[chunk * 8];
        s[t] = __builtin_amdgcn_mfma_f32_16x16x32_bf16(kf, qf[ks], s[t], 0, 0, 0);
      }
    }

    // mask + row max (scale already folded into qh)
    float zm = -1e30f;
#pragma unroll
    for (int t = 0; t < 4; ++t) {
      int kb = k0 + t * 16 + lq * 4;
#pragma unroll
      for (int r = 0; r < 4; ++r) {
        if (kb + r >= vl) s[t][r] = -1e30f;
        zm = fmaxf(zm, s[t][r]);
      }
    }
    zm = fmaxf(zm, __shfl_xor(zm, 16));
    zm = fmaxf(zm, __shfl_xor(zm, 32));
    float mnew  = fmaxf(mold, zm);
    float alpha = exp2f(mold - mnew);
    float rs = 0.f;
    bf16x4 sb[4];
#pragma unroll
    for (int t = 0; t < 4; ++t)
#pragma unroll
      for (int r = 0; r < 4; ++r) {
        float p = exp2f(s[t][r] - mnew);   // masked -> exactly 0
        rs += p;
        sb[t][r] = (bf16)p;
      }
    rs += __shfl_xor(rs, 16);
    rs += __shfl_xor(rs, 32);
    lsum = lsum * alpha + rs;
    mold = mnew;
#pragma unroll
    for (int mt = 0; mt < 4; ++mt) {
      acc[mt][0] *= alpha; acc[mt][1] *= alpha;
      acc[mt][2] *= alpha; acc[mt][3] *= alpha;
    }

    // O^T += V^T · P : A = V^T rows (m=dh), B = P (keys k=quad*8+j)
#pragma unroll
    for (int p = 0; p < 2; ++p) {
      bf16x8 pb;
#pragma unroll
      for (int r = 0; r < 4; ++r) { pb[r] = sb[2 * p][r]; pb[4 + r] = sb[2 * p + 1][r]; }
#pragma unroll
      for (int mt = 0; mt < 4; ++mt) {
        int row = mt * 16 + lrow;
        int cc0 = p * 4 + (lq >> 1);
        int e0 = (row * 8 + (cc0 ^ rx)) * 8 + (lq & 1) * 4;
        int e1 = (row * 8 + ((cc0 + 2) ^ rx)) * 8 + (lq & 1) * 4;
        bf16x4 v0 = *(const bf16x4*)&bufV[e0];
        bf16x4 v1 = *(const bf16x4*)&bufV[e1];
        bf16x8 vf;
#pragma unroll
        for (int r = 0; r < 4; ++r) { vf[r] = v0[r]; vf[4 + r] = v1[r]; }
        acc[mt] = __builtin_amdgcn_mfma_f32_16x16x32_bf16(vf, pb, acc[mt], 0, 0, 0);
      }
    }
  }

  // epilogue: O^T C-layout col=query=lrow, row=dh=mt*16+lq*4+r
  float inv = 1.0f / lsum;
  int qrow = q0 + lrow;
#pragma unroll
  for (int mt = 0; mt < 4; ++mt) {
    bf16x4 o;
#pragma unroll
    for (int r = 0; r < 4; ++r) o[r] = (bf16)(acc[mt][r] * inv);
    *(bf16x4*)&ao[(size_t)(b * QQ + qrow) * DD + h * DHH + mt * 16 + lq * 4] = o;
  }
}

extern "C" void kernel_launch(void* const* d_in, const int* in_sizes, int n_in,
                              void* d_out, int out_size, void* d_ws, size_t ws_size,
                              hipStream_t stream) {
  const float* queries    = (const float*)d_in[0];
  const float* keys       = (const float*)d_in[1];
  const float* values     = (const float*)d_in[2];
  const int*   valid_lens = (const int*)d_in[3];
  const float* W_q = (const float*)d_in[4];
  const float* W_k = (const float*)d_in[5];
  const float* W_v = (const float*)d_in[6];
  const float* W_o = (const float*)d_in[7];

  const size_t NX = (size_t)BB * QQ * DD;   // 4194304
  const size_t NW = (size_t)DD * DD;        // 262144

  bf16* xq = (bf16*)d_ws;       // bf16 inputs
  bf16* xk = xq + NX;
  bf16* xv = xk + NX;
  bf16* wq = xv + NX;           // bf16 weights
  bf16* wk = wq + NW;
  bf16* wv = wk + NW;
  bf16* wo = wv + NW;
  bf16* qh = wo + NW;           // [B,H,S,DH] (pre-scaled by 1/8*log2e)
  bf16* kh = qh + NX;           // [B,H,S,DH]
  bf16* vt = kh + NX;           // [B,H,DH,S]
  bf16* ao = xq;                // reuse xq region (projections finished)

  dim3 blk(256);
  cvt3<<<dim3(NX / 1024, 3), blk, 0, stream>>>(queries, keys, values,
                                               xq, xk, xv, (int)(NX / 4));
  cvt4<<<dim3(NW / 1024, 4), blk, 0, stream>>>(W_q, W_k, W_v, W_o,
                                               wq, wk, wv, wo, (int)(NW / 4));

  dim3 gg(DD / 64, (BB * QQ) / 128);   // (8, 64) = 512 blocks
  const float qscale = 0.125f * 1.44269504088896340736f;  // 1/sqrt(64)*log2e
  gemm_bt<0><<<gg, blk, 0, stream>>>(xq, wq, qh, qscale);
  gemm_bt<0><<<gg, blk, 0, stream>>>(xk, wk, kh, 1.0f);
  gemm_bt<2><<<gg, blk, 0, stream>>>(xv, wv, vt, 1.0f);

  attn<<<dim3(QQ / 64, BB * HH), blk, 0, stream>>>(qh, kh, vt, valid_lens, ao);

  gemm_bt<1><<<gg, blk, 0, stream>>>(ao, wo, d_out, 1.0f);
}